// Round 1
// baseline (400.102 us; speedup 1.0000x reference)
//
#include <hip/hip_runtime.h>
#include <stdint.h>

#define B_ 16
#define C_ 64
#define H_ 112
#define W_ 112
#define N_ 256

typedef __attribute__((ext_vector_type(8))) short short8;
typedef __attribute__((ext_vector_type(4))) float floatx4;

__device__ __forceinline__ uint32_t f2bf_bits(float f) {
  uint32_t u = __float_as_uint(f);
  return (u + 0x7fffu + ((u >> 16) & 1u)) >> 16;  // RNE f32 -> bf16 bits
}

// NCHW f32 -> [b][i][j][c] packed uint32: low16 = bf16(x), high16 = bf16(x^2)
__global__ __launch_bounds__(256) void xform_x(const float* __restrict__ x,
                                               uint32_t* __restrict__ xq) {
  __shared__ float ls[64][113];  // +1 pad: odd stride -> conflict-free transpose read
  int bi = blockIdx.x;
  int b = bi / H_, i = bi % H_;
  const float* xbase = x + ((size_t)b * C_) * (H_ * W_) + (size_t)i * W_;
  for (int idx = threadIdx.x; idx < C_ * W_; idx += 256) {
    int c = idx / W_, j = idx - c * W_;
    ls[c][j] = xbase[(size_t)c * (H_ * W_) + j];
  }
  __syncthreads();
  uint32_t* orow = xq + ((size_t)(b * H_ + i)) * (W_ * C_);
  for (int idx = threadIdx.x; idx < W_ * C_; idx += 256) {
    int j = idx >> 6, c = idx & 63;
    float v = ls[c][j];
    float v2 = v * v;
    orow[idx] = f2bf_bits(v) | (f2bf_bits(v2) << 16);
  }
}

// Weights -> Wg[cg(2)][tap(9)][kk(2)][n(256)][pos(16)] uint32 pairs:
//   low16 = bf16(2*|w|*t) (multiplies x), high16 = bf16(-|w|) (multiplies x^2)
// Layout makes one wave's A-fragment load ((n..n+15) x 64B) fully contiguous (1KB).
// Also computes cN[n] = sum |w| t^2 (fused, one block per n).
__global__ __launch_bounds__(64) void prep_wc(const float* __restrict__ sw,
                                              const float* __restrict__ tp,
                                              uint32_t* __restrict__ Wg,
                                              float* __restrict__ cN) {
  int n = blockIdx.x, c = threadIdx.x;  // c = 0..63
  int cg = c >> 5, ci = c & 31;
  int kk = ci >> 4, pos = ci & 15;
  const float* swp = sw + (size_t)(n * C_ + c) * 9;
  const float* tpp = tp + (size_t)(n * C_ + c) * 9;
  float s = 0.f;
#pragma unroll
  for (int tap = 0; tap < 9; ++tap) {
    float w = fabsf(swp[tap]);
    float t = tpp[tap];
    s += w * t * t;
    uint32_t v = f2bf_bits(2.0f * w * t) | (f2bf_bits(-w) << 16);
    Wg[(size_t)(((cg * 9 + tap) * 2 + kk) * (N_ * 16)) + n * 16 + pos] = v;
  }
#pragma unroll
  for (int off = 32; off > 0; off >>= 1) s += __shfl_down(s, off);
  if (c == 0) cN[n] = s;
}

// Output tile: 128 n x 256 pixels (16 rows x 16 cols). 512 threads = 8 waves,
// each wave: 64 n x 4 rows x 16 cols, acc 4x4 fragments (64V + 64A, same as before).
// vs previous 128x128 tile: weight L2 traffic per output HALVES and each A-fragment
// is shared by 4 waves (L1 hits); x-halo overhead also drops (18x18 vs 2x 10x18).
// LDS x tile is XOR-swizzled (chunk ch of site s stored at ch^(s&7), site stride
// exactly 128B, no pad) -> both staging uint4 writes and ds_read_b128 B-fragment
// reads are bank-conflict-free (was ~4-way, 7.2M conflict cycles).
__global__ __launch_bounds__(512, 4) void sim_main(const uint32_t* __restrict__ xq,
                                                   const uint32_t* __restrict__ Wg,
                                                   const float* __restrict__ cN,
                                                   float* __restrict__ out) {
  __shared__ uint32_t xs[18 * 18 * 32];  // 324 halo sites x 128B, swizzled chunks

  int bx = blockIdx.x;
  int nb = bx & 1;
  bx >>= 1;
  int b = bx / 49;
  int rem = bx - b * 49;
  int rt = rem / 7, ct = rem - rt * 7;
  int r0 = rt * 16, c0 = ct * 16;
  int tid = threadIdx.x;
  int lane = tid & 63, wv = tid >> 6;
  int wn = wv & 1, wp = wv >> 1;  // wn: which 64-n half, wp: which 4-row group
  int l15 = lane & 15, l4 = lane >> 4;

  floatx4 acc[4][4];  // [nt][pt]; D row = n (l4*4+reg), D col = pixel (l15)
#pragma unroll
  for (int a = 0; a < 4; ++a)
#pragma unroll
    for (int p = 0; p < 4; ++p) acc[a][p] = (floatx4){0.f, 0.f, 0.f, 0.f};

  const uint32_t* xim = xq + (size_t)b * (H_ * W_ * C_);
  // per-lane A-fragment base (row n = nb*128+wn*64+l15, dwords l4*4..l4*4+3)
  const uint32_t* wlane = Wg + (nb * 128 + wn * 64 + l15) * 16 + l4 * 4;

  for (int cg = 0; cg < 2; ++cg) {
    if (cg) __syncthreads();  // prior cg's xs readers done before overwrite
    // stage 18x18 halo sites, 32 channels (128B) each, zero-filled out of bounds;
    // 16B chunk ch of site s lands at slot ch^(s&7)  (conflict-free write & read)
    for (int idx = tid; idx < 324 * 8; idx += 512) {
      int s = idx >> 3, ch = idx & 7;
      int row = s / 18, col = s - row * 18;
      int gi = r0 - 1 + row, gj = c0 - 1 + col;
      uint4 v = make_uint4(0u, 0u, 0u, 0u);
      if ((unsigned)gi < (unsigned)H_ && (unsigned)gj < (unsigned)W_)
        v = *(const uint4*)(xim + ((size_t)(gi * W_ + gj)) * C_ + cg * 32 + ch * 4);
      *(uint4*)(&xs[s * 32 + ((ch ^ (s & 7)) << 2)]) = v;
    }
    __syncthreads();

#pragma unroll 1
    for (int tap = 0; tap < 9; ++tap) {
      int dp = tap / 3, dq = tap - dp * 3;
      const uint32_t* wp0 = wlane + (size_t)((cg * 9 + tap) * 2) * (N_ * 16);
      int sb[4], sx[4];  // per-pt site base (dwords) and swizzle key; kk-invariant
#pragma unroll
      for (int pt = 0; pt < 4; ++pt) {
        int s = (wp * 4 + pt + dp) * 18 + l15 + dq;
        sb[pt] = s * 32;
        sx[pt] = s & 7;
      }
#pragma unroll
      for (int kk = 0; kk < 2; ++kk) {  // only 8 frags live at a time (32 VGPRs)
        int chb = kk * 4 + l4;
        short8 af[4], bfr[4];
#pragma unroll
        for (int nt = 0; nt < 4; ++nt)
          af[nt] = *(const short8*)(wp0 + (size_t)kk * (N_ * 16) + nt * 16 * 16);
#pragma unroll
        for (int pt = 0; pt < 4; ++pt)
          bfr[pt] = *(const short8*)(&xs[sb[pt] + ((chb ^ sx[pt]) << 2)]);
#pragma unroll
        for (int nt = 0; nt < 4; ++nt)
#pragma unroll
          for (int pt = 0; pt < 4; ++pt)
            acc[nt][pt] =
                __builtin_amdgcn_mfma_f32_16x16x32_bf16(af[nt], bfr[pt], acc[nt][pt], 0, 0, 0);
      }
    }
  }

  // epilogue: out[b][n][r][col] = acc - const[n]; lanes 0..15 -> consecutive cols
#pragma unroll
  for (int nt = 0; nt < 4; ++nt) {
#pragma unroll
    for (int v = 0; v < 4; ++v) {
      int n = nb * 128 + wn * 64 + nt * 16 + l4 * 4 + v;
      float cv = cN[n];
#pragma unroll
      for (int pt = 0; pt < 4; ++pt) {
        int r = r0 + wp * 4 + pt;
        int col = c0 + l15;
        out[(((size_t)b * N_ + n) * H_ + r) * W_ + col] = acc[nt][pt][v] - cv;
      }
    }
  }
}

extern "C" void kernel_launch(void* const* d_in, const int* in_sizes, int n_in,
                              void* d_out, int out_size, void* d_ws, size_t ws_size,
                              hipStream_t stream) {
  const float* x = (const float*)d_in[0];
  const float* sw = (const float*)d_in[1];
  const float* tp = (const float*)d_in[2];
  float* out = (float*)d_out;

  // workspace layout
  const size_t xq_bytes = (size_t)B_ * H_ * W_ * C_ * 4;    // 51,380,224
  const size_t wg_bytes = (size_t)2 * 9 * 2 * N_ * 16 * 4;  // 589,824
  uint32_t* xq = (uint32_t*)d_ws;
  uint32_t* Wg = (uint32_t*)((char*)d_ws + xq_bytes);
  float* cN = (float*)((char*)d_ws + xq_bytes + wg_bytes);

  xform_x<<<dim3(B_ * H_), dim3(256), 0, stream>>>(x, xq);
  prep_wc<<<dim3(N_), dim3(64), 0, stream>>>(sw, tp, Wg, cN);
  sim_main<<<dim3(2 * B_ * 7 * 7), dim3(512), 0, stream>>>(xq, Wg, cN, out);
}

// Round 2
// 380.886 us; speedup vs baseline: 1.0504x; 1.0504x over previous
//
#include <hip/hip_runtime.h>
#include <stdint.h>

#define B_ 16
#define C_ 64
#define H_ 112
#define W_ 112
#define N_ 256

typedef __attribute__((ext_vector_type(8))) short short8;
typedef __attribute__((ext_vector_type(4))) float floatx4;

typedef __attribute__((address_space(1))) const uint32_t gas_u32;
typedef __attribute__((address_space(3))) uint32_t las_u32;

__device__ __forceinline__ uint32_t f2bf_bits(float f) {
  uint32_t u = __float_as_uint(f);
  return (u + 0x7fffu + ((u >> 16) & 1u)) >> 16;  // RNE f32 -> bf16 bits
}

// NCHW f32 -> [b][i][j][c] packed uint32: low16 = bf16(x), high16 = bf16(x^2)
__global__ __launch_bounds__(256) void xform_x(const float* __restrict__ x,
                                               uint32_t* __restrict__ xq) {
  __shared__ float ls[64][113];  // +1 pad: odd stride -> conflict-free transpose read
  int bi = blockIdx.x;
  int b = bi / H_, i = bi % H_;
  const float* xbase = x + ((size_t)b * C_) * (H_ * W_) + (size_t)i * W_;
  for (int idx = threadIdx.x; idx < C_ * W_; idx += 256) {
    int c = idx / W_, j = idx - c * W_;
    ls[c][j] = xbase[(size_t)c * (H_ * W_) + j];
  }
  __syncthreads();
  uint32_t* orow = xq + ((size_t)(b * H_ + i)) * (W_ * C_);
  for (int idx = threadIdx.x; idx < W_ * C_; idx += 256) {
    int j = idx >> 6, c = idx & 63;
    float v = ls[c][j];
    float v2 = v * v;
    orow[idx] = f2bf_bits(v) | (f2bf_bits(v2) << 16);
  }
}

// Weights -> Wg[cg(2)][tap(9)][kk(2)][n(256)][pos(16)] uint32 pairs:
//   low16 = bf16(2*|w|*t) (multiplies x), high16 = bf16(-|w|) (multiplies x^2)
// Per (cg,tap,kk) the 128-n half a block needs is a contiguous 8KB slice ->
// stageable with global_load_lds (wave-uniform dest + lane*16).
// Also computes cN[n] = sum |w| t^2 (fused, one block per n).
__global__ __launch_bounds__(64) void prep_wc(const float* __restrict__ sw,
                                              const float* __restrict__ tp,
                                              uint32_t* __restrict__ Wg,
                                              float* __restrict__ cN) {
  int n = blockIdx.x, c = threadIdx.x;  // c = 0..63
  int cg = c >> 5, ci = c & 31;
  int kk = ci >> 4, pos = ci & 15;
  const float* swp = sw + (size_t)(n * C_ + c) * 9;
  const float* tpp = tp + (size_t)(n * C_ + c) * 9;
  float s = 0.f;
#pragma unroll
  for (int tap = 0; tap < 9; ++tap) {
    float w = fabsf(swp[tap]);
    float t = tpp[tap];
    s += w * t * t;
    uint32_t v = f2bf_bits(2.0f * w * t) | (f2bf_bits(-w) << 16);
    Wg[(size_t)(((cg * 9 + tap) * 2 + kk) * (N_ * 16)) + n * 16 + pos] = v;
  }
#pragma unroll
  for (int off = 32; off > 0; off >>= 1) s += __shfl_down(s, off);
  if (c == 0) cN[n] = s;
}

// Output tile: 128 n x 256 pixels (16x16). 512 threads = 8 waves, each 64n x 4r x 16c.
// r1 post-mortem: latency-bound (MfmaUtil 26% ~= MFMA-floor busy time, no pipe
// saturated, VGPR-capped occupancy 3-4 waves/SIMD, compiler serialized the global
// weight loads -> every tap stalls ~200-300cy on L2). Fix: NO global loads in the
// inner loop. Weights staged to LDS kk-slice (8KB) at a time via global_load_lds,
// double-buffered, issued one full compute step (~400cy) ahead so the barrier's
// vmcnt drain is free (T3-lite). Inner loop waits only on LDS.
__global__ __launch_bounds__(512, 4) void sim_main(const uint32_t* __restrict__ xq,
                                                   const uint32_t* __restrict__ Wg,
                                                   const float* __restrict__ cN,
                                                   float* __restrict__ out) {
  __shared__ uint32_t xs[18 * 18 * 32];  // 41472B halo tile, XOR-swizzled chunks
  __shared__ uint32_t ws[2 * 2048];      // 2 x 8KB weight kk-slice double buffer

  int bx = blockIdx.x;
  int nb = bx & 1;
  bx >>= 1;
  int b = bx / 49;
  int rem = bx - b * 49;
  int rt = rem / 7, ct = rem - rt * 7;
  int r0 = rt * 16, c0 = ct * 16;
  int tid = threadIdx.x;
  int lane = tid & 63, wv = tid >> 6;
  int wn = wv & 1, wp = wv >> 1;  // wn: which 64-n half, wp: which 4-row group
  int l15 = lane & 15, l4 = lane >> 4;

  floatx4 acc[4][4];  // [nt][pt]; D row = n (l4*4+reg), D col = pixel (l15)
#pragma unroll
  for (int a = 0; a < 4; ++a)
#pragma unroll
    for (int p = 0; p < 4; ++p) acc[a][p] = (floatx4){0.f, 0.f, 0.f, 0.f};

  const uint32_t* xim = xq + (size_t)b * (H_ * W_ * C_);
  const uint32_t* wslice = Wg + nb * 2048;  // + s*(N_*16) per kk-step

  // stage 18x18 halo sites, 32 channels (128B) each, zero-filled out of bounds;
  // 16B chunk ch of site s lands at slot ch^(s&7)  (conflict-free write & read)
  auto stage_xs = [&](int cg) {
    for (int idx = tid; idx < 324 * 8; idx += 512) {
      int s = idx >> 3, ch = idx & 7;
      int row = s / 18, col = s - row * 18;
      int gi = r0 - 1 + row, gj = c0 - 1 + col;
      uint4 v = make_uint4(0u, 0u, 0u, 0u);
      if ((unsigned)gi < (unsigned)H_ && (unsigned)gj < (unsigned)W_)
        v = *(const uint4*)(xim + ((size_t)(gi * W_ + gj)) * C_ + cg * 32 + ch * 4);
      *(uint4*)(&xs[s * 32 + ((ch ^ (s & 7)) << 2)]) = v;
    }
  };
  // stage weight kk-slice step -> ws[step&1]; per wave: 1KB linear (lds dest is
  // wave-uniform base + lane*16, global src per-lane) -- one issue per thread
  auto stage_w = [&](int step) {
    const uint32_t* g = wslice + (size_t)step * (N_ * 16) + wv * 256 + lane * 4;
    uint32_t* l = &ws[(step & 1) * 2048 + wv * 256];
    __builtin_amdgcn_global_load_lds((gas_u32*)g, (las_u32*)l, 16, 0, 0);
  };

  // prologue: xs for cg=0, weights for step 0
  stage_xs(0);
  stage_w(0);
  __syncthreads();

  int awb = (wn * 64 + l15) * 16 + l4 * 4;  // A-frag dword base within kk-slice

#pragma unroll 1
  for (int s = 0; s < 36; ++s) {  // s = cg*18 + tap*2 + kk
    if (s < 35) stage_w(s + 1);   // prefetch next slice; lands before next barrier
    if (s == 18) {                // cg boundary: old-xs readers done (barrier @17)
      stage_xs(1);
      __syncthreads();
    }
    int t2 = (s < 18) ? s : s - 18;
    int tap = t2 >> 1, kk = t2 & 1;
    int dp = tap / 3, dq = tap - dp * 3;
    int chb = kk * 4 + l4;
    int buf = s & 1;

    short8 af[4], bfr[4];
#pragma unroll
    for (int nt = 0; nt < 4; ++nt)
      af[nt] = *(const short8*)(&ws[buf * 2048 + awb + nt * 256]);
#pragma unroll
    for (int pt = 0; pt < 4; ++pt) {
      int st = (wp * 4 + pt + dp) * 18 + l15 + dq;
      bfr[pt] = *(const short8*)(&xs[st * 32 + ((chb ^ (st & 7)) << 2)]);
    }
#pragma unroll
    for (int nt = 0; nt < 4; ++nt)
#pragma unroll
      for (int pt = 0; pt < 4; ++pt)
        acc[nt][pt] =
            __builtin_amdgcn_mfma_f32_16x16x32_bf16(af[nt], bfr[pt], acc[nt][pt], 0, 0, 0);
    if (s < 35) __syncthreads();  // next step's ws slice valid after this
  }

  // epilogue: out[b][n][r][col] = acc - const[n]; lanes 0..15 -> consecutive cols
#pragma unroll
  for (int nt = 0; nt < 4; ++nt) {
#pragma unroll
    for (int v = 0; v < 4; ++v) {
      int n = nb * 128 + wn * 64 + nt * 16 + l4 * 4 + v;
      float cv = cN[n];
#pragma unroll
      for (int pt = 0; pt < 4; ++pt) {
        int r = r0 + wp * 4 + pt;
        int col = c0 + l15;
        out[(((size_t)b * N_ + n) * H_ + r) * W_ + col] = acc[nt][pt][v] - cv;
      }
    }
  }
}

extern "C" void kernel_launch(void* const* d_in, const int* in_sizes, int n_in,
                              void* d_out, int out_size, void* d_ws, size_t ws_size,
                              hipStream_t stream) {
  const float* x = (const float*)d_in[0];
  const float* sw = (const float*)d_in[1];
  const float* tp = (const float*)d_in[2];
  float* out = (float*)d_out;

  // workspace layout
  const size_t xq_bytes = (size_t)B_ * H_ * W_ * C_ * 4;    // 51,380,224
  const size_t wg_bytes = (size_t)2 * 9 * 2 * N_ * 16 * 4;  // 589,824
  uint32_t* xq = (uint32_t*)d_ws;
  uint32_t* Wg = (uint32_t*)((char*)d_ws + xq_bytes);
  float* cN = (float*)((char*)d_ws + xq_bytes + wg_bytes);

  xform_x<<<dim3(B_ * H_), dim3(256), 0, stream>>>(x, xq);
  prep_wc<<<dim3(N_), dim3(64), 0, stream>>>(sw, tp, Wg, cN);
  sim_main<<<dim3(2 * B_ * 7 * 7), dim3(512), 0, stream>>>(xq, Wg, cN, out);
}